// Round 6
// baseline (5072.332 us; speedup 1.0000x reference)
//
#include <hip/hip_runtime.h>
#include <stdint.h>

// MoleculeDecoder r6: minimal-round-trip persistent kernel.
// r5 post-mortem: sync DETECTION wasn't the cost; serial L3 round-trips and
// role imbalance were. r6: combine blocks own W_hh rows in VGPRs (gh computed
// locally, gh_buf RT gone); vocab argmax via global atomicMax into 32 rotating
// slots + monotonic arrive counter (cand gather gone); h ready via one
// monotonic hdone counter. ~3 serial RTs/step.

typedef unsigned long long u64;
typedef unsigned int u32;
typedef _Float16 f16;
using half8 = __attribute__((ext_vector_type(8))) _Float16;
using f32x4 = __attribute__((ext_vector_type(4))) float;
using uint4v = __attribute__((ext_vector_type(4))) unsigned int;

#define E_ 768
#define V_ 8192
#define T_ 256
#define HP 24576            // 32*768 (one h plane, elements)
#define IH_PLANE (2304*768)
#define OUT_PLANE (8192*768)
#define NBLK 256
#define NCMB 48             // combine blocks (e-slices of 16)

#define AGENT_LD(p)    __hip_atomic_load((p), __ATOMIC_RELAXED, __HIP_MEMORY_SCOPE_AGENT)
#define AGENT_ST(p,v)  __hip_atomic_store((p), (v), __ATOMIC_RELAXED, __HIP_MEMORY_SCOPE_AGENT)
#define AGENT_ADD(p,v) __hip_atomic_fetch_add((p), (v), __ATOMIC_RELAXED, __HIP_MEMORY_SCOPE_AGENT)

__device__ __forceinline__ f32x4 mfma16(half8 a, half8 b, f32x4 c){
  return __builtin_amdgcn_mfma_f32_16x16x32_f16(a, b, c, 0, 0, 0);
}
__device__ __forceinline__ void split2(float f, f16& hi, f16& lo){
  f16 h = (f16)f; hi = h; lo = (f16)((f - (float)h) * 4096.0f);
}
__device__ __forceinline__ u32 packh(float f){
  f16 h, l; split2(f, h, l);
  return (u32)__builtin_bit_cast(unsigned short, h) |
         ((u32)__builtin_bit_cast(unsigned short, l) << 16);
}
__device__ __forceinline__ u64 packkey(float f, int v){
  u32 fb = __float_as_uint(f);
  u32 s  = fb ^ ((u32)((int32_t)fb>>31) | 0x80000000u);
  return ((u64)s<<32) | (u64)(0xFFFFFFFFu - (u32)v);   // ties -> smaller idx wins
}

// ---------------- prep: split weights; h0; zero counters+slots ----------------
#define NB_CONV 1200
#define NB_H0   96
#define NG_IH   221184      // 2304*768/8
#define NG_ALL  1228800     // (2*2304 + 8192)*768/8

__global__ __launch_bounds__(256) void prep_k(
    const float* __restrict__ W_ih, const float* __restrict__ W_hh, const float* __restrict__ W_out,
    const float* __restrict__ latent, const float* __restrict__ W_lat, const float* __restrict__ b_lat,
    f16* __restrict__ Wih_s, f16* __restrict__ Whh_s, f16* __restrict__ Wout_s,
    float* __restrict__ h_f32, u32* __restrict__ h_pack,
    u64* __restrict__ slots32, unsigned* __restrict__ bar)
{
  int blk = blockIdx.x;
  if (blk < NB_CONV){
    for (int g = blk*256 + threadIdx.x; g < NG_ALL; g += NB_CONV*256){
      const float* src; f16* hi; f16* lo; int off;
      if (g < NG_IH)        { src=W_ih; hi=Wih_s; lo=Wih_s+IH_PLANE; off=g*8; }
      else if (g < 2*NG_IH) { src=W_hh; hi=Whh_s; lo=Whh_s+IH_PLANE; off=(g-NG_IH)*8; }
      else                  { src=W_out; hi=Wout_s; lo=Wout_s+OUT_PLANE; off=(g-2*NG_IH)*8; }
      float4 a = *(const float4*)(src+off);
      float4 b = *(const float4*)(src+off+4);
      float fs[8] = {a.x,a.y,a.z,a.w,b.x,b.y,b.z,b.w};
      half8 vh, vl;
      #pragma unroll
      for (int j=0;j<8;j++){ f16 h,l; split2(fs[j],h,l); vh[j]=h; vl[j]=l; }
      *(half8*)(hi+off) = vh;
      *(half8*)(lo+off) = vl;
    }
  } else {
    if (blk==NB_CONV){
      if (threadIdx.x < 64)  bar[threadIdx.x] = 0;
      if (threadIdx.x < 128) slots32[threadIdx.x] = 0;
    }
    int tid = (blk-NB_CONV)*256 + threadIdx.x;     // 0..24575
    int b = tid/768, e = tid - b*768;
    const float4* wr = (const float4*)(W_lat + (size_t)e*768);
    const float4* xr = (const float4*)(latent + (size_t)b*768);
    float s0=0.f,s1=0.f,s2=0.f,s3=0.f;
    for (int k=0;k<192;k++){
      float4 w = wr[k]; float4 x = xr[k];
      s0 += w.x*x.x; s1 += w.y*x.y; s2 += w.z*x.z; s3 += w.w*x.w;
    }
    float acc = b_lat[e] + ((s0+s1)+(s2+s3));
    h_f32[b*768+e] = acc;
    h_pack[b*768+e] = packh(acc);
  }
}

// ---------------- gi table: gi_tab[tok][2304] = (W_ih @ emb[tok])  (no bias), f32 ----------------
__global__ __launch_bounds__(512) void gitab_k(
    const float* __restrict__ emb, const f16* __restrict__ Wih_s, float* __restrict__ gi_tab)
{
  __shared__ float red[3][8][2][64][4];
  const int bid = blockIdx.x, tid = threadIdx.x;
  const int tb = bid>>1, half = bid&1;
  const int w = tid>>6, lane = tid&63, col = lane&15, kg = lane>>4, kc = w;
  half8 ah[2][3], al[2][3];
  #pragma unroll
  for (int m=0;m<2;m++)
    #pragma unroll
    for (int i=0;i<3;i++){
      const float* src = emb + (size_t)(tb*32 + m*16 + col)*768 + kc*96 + i*32 + kg*8;
      float4 x0 = *(const float4*)src, x1 = *(const float4*)(src+4);
      float fs[8] = {x0.x,x0.y,x0.z,x0.w,x1.x,x1.y,x1.z,x1.w};
      half8 vh, vl;
      #pragma unroll
      for (int j=0;j<8;j++){ f16 h,l; split2(fs[j],h,l); vh[j]=h; vl[j]=l; }
      ah[m][i]=vh; al[m][i]=vl;
    }
  for (int g=0; g<24; ++g){
    #pragma unroll
    for (int j=0;j<3;j++){
      const int nt = half*72 + g*3 + j;
      f32x4 a0[2], a1[2];
      #pragma unroll
      for (int m=0;m<2;m++){ a0[m]=f32x4{0,0,0,0}; a1[m]=f32x4{0,0,0,0}; }
      #pragma unroll
      for (int i=0;i<3;i++){
        size_t o = (size_t)(nt*16+col)*768 + kc*96 + i*32 + kg*8;
        half8 bh = *(const half8*)(Wih_s + o);
        half8 bl = *(const half8*)(Wih_s + IH_PLANE + o);
        #pragma unroll
        for (int m=0;m<2;m++){
          a0[m] = mfma16(ah[m][i], bh, a0[m]);
          a1[m] = mfma16(ah[m][i], bl, a1[m]);
          a1[m] = mfma16(al[m][i], bh, a1[m]);
        }
      }
      #pragma unroll
      for (int m=0;m<2;m++){
        f32x4 v;
        #pragma unroll
        for (int r=0;r<4;r++) v[r] = a0[m][r] + a1[m][r]*(1.0f/4096.0f);
        *(f32x4*)&red[j][w][m][lane][0] = v;
      }
    }
    __syncthreads();
    if (w < 6){
      const int j = w>>1, m = w&1;
      f32x4 s = {0,0,0,0};
      #pragma unroll
      for (int ww=0; ww<8; ww++) s += *(const f32x4*)&red[j][ww][m][lane][0];
      const int nt = half*72 + g*3 + j;
      const int tokr = tb*32 + m*16 + kg*4;
      #pragma unroll
      for (int r=0;r<4;r++)
        gi_tab[(size_t)(tokr+r)*2304 + nt*16 + col] = s[r];
    }
    __syncthreads();
  }
}

// ---------------- counter poll: whole wave, one address, relaxed coherent ----------------
__device__ __forceinline__ void poll_cnt(unsigned* p, u32 want){
  int spins = 0;
  while (AGENT_LD(p) < want){
    __builtin_amdgcn_s_sleep(1);
    if ((++spins & 4095) == 0) AGENT_ADD(p, 0u);   // liveness insurance
  }
}

// ---------------- persistent decode kernel (cooperative, 256 x 512) ----------------
// bar[0] = arrive counter (monotonic, +256/step); bar[32] = hdone (+48/step).
// slots32[4][32]: per-step-parity global argmax slots (u64 atomicMax).
__global__ __launch_bounds__(512, 2) void decode_k(
    const f16* __restrict__ Wout_s, const f16* __restrict__ Whh_s, const float* __restrict__ gi_tab,
    const float* __restrict__ h_f32, u32* __restrict__ h_pack, u64* __restrict__ slots32,
    const float* __restrict__ b_ih, const float* __restrict__ b_hh,
    const float* __restrict__ b_out, float* __restrict__ out, unsigned* __restrict__ bar)
{
  __shared__ float red[2][8][2][64][4];    // 16 KB logits K-partials
  __shared__ float redg[3][8][2][64][4];   // 24 KB gh K-partials (combine blocks)
  __shared__ float ghl[3][32][17];         // reduced gh [gate][b][e-off]
  __shared__ u64 amkey[32];
  const int bid = blockIdx.x, tid = threadIdx.x;
  const int w = tid>>6, lane = tid&63, col = lane&15, kg = lane>>4, kc = w;
  const bool is_cmb = (bid < NCMB);

  // ---- persistent logits B fragments (2 slots: cols bid*16, 4096+bid*16) ----
  half8 bf_h[2][3], bf_l[2][3];
  #pragma unroll
  for (int s=0;s<2;s++)
    #pragma unroll
    for (int i=0;i<3;i++){
      size_t o = (size_t)(s*4096 + bid*16 + col)*768 + kc*96 + i*32 + kg*8;
      bf_h[s][i] = *(const half8*)(Wout_s + o);
      bf_l[s][i] = *(const half8*)(Wout_s + OUT_PLANE + o);
    }
  // ---- persistent gh B fragments (combine blocks: rows g*768 + bid*16+col) ----
  half8 gw_h[3][3], gw_l[3][3];
  if (is_cmb){
    #pragma unroll
    for (int g=0;g<3;g++)
      #pragma unroll
      for (int i=0;i<3;i++){
        size_t o = (size_t)(g*768 + bid*16 + col)*768 + kc*96 + i*32 + kg*8;
        gw_h[g][i] = *(const half8*)(Whh_s + o);
        gw_l[g][i] = *(const half8*)(Whh_s + IH_PLANE + o);
      }
  }
  float bo_reg[2];
  bo_reg[0] = b_out[bid*16 + col];
  bo_reg[1] = b_out[4096 + bid*16 + col];

  // combine ownership: thread -> (batch cb, element ce = bid*16 + (tid&15))
  int cb = 0, ce = 0; float hreg = 0.f;
  float bir=0,biz=0,bin_=0,bhr=0,bhz=0,bhn=0;
  if (is_cmb){
    cb = tid>>4; ce = bid*16 + (tid&15);
    hreg = h_f32[cb*768 + ce];
    bir=b_ih[ce]; biz=b_ih[768+ce]; bin_=b_ih[1536+ce];
    bhr=b_hh[ce]; bhz=b_hh[768+ce]; bhn=b_hh[1536+ce];
  }

  for (int t=0; t<=256; ++t){
    // =================== phase A ===================
    if (tid < 32) amkey[tid] = 0;
    u64 q[2][3][4];
    #pragma unroll
    for (int m=0;m<2;m++)
      #pragma unroll
      for (int i=0;i<3;i++){
        const int row = m*16 + col, k0 = kc*96 + i*32 + kg*8;
        const u64* hp = (const u64*)(h_pack + row*768 + k0);
        #pragma unroll
        for (int j=0;j<4;j++) q[m][i][j] = AGENT_LD(hp+j);
      }
    half8 ah[2][3], al[2][3];
    #pragma unroll
    for (int m=0;m<2;m++)
      #pragma unroll
      for (int i=0;i<3;i++){
        uint4v wh, wl;
        #pragma unroll
        for (int j=0;j<4;j++){
          u32 w0 = (u32)q[m][i][j], w1 = (u32)(q[m][i][j]>>32);
          wh[j] = (w0 & 0xffffu) | (w1 << 16);
          wl[j] = (w0 >> 16) | (w1 & 0xffff0000u);
        }
        ah[m][i] = __builtin_bit_cast(half8, wh);
        al[m][i] = __builtin_bit_cast(half8, wl);
      }
    #pragma unroll
    for (int s=0;s<2;s++){
      f32x4 a0[2], a1[2];
      #pragma unroll
      for (int m=0;m<2;m++){ a0[m]=f32x4{0,0,0,0}; a1[m]=f32x4{0,0,0,0}; }
      #pragma unroll
      for (int i=0;i<3;i++)
        #pragma unroll
        for (int m=0;m<2;m++){
          a0[m] = mfma16(ah[m][i], bf_h[s][i], a0[m]);
          a1[m] = mfma16(ah[m][i], bf_l[s][i], a1[m]);
          a1[m] = mfma16(al[m][i], bf_h[s][i], a1[m]);
        }
      #pragma unroll
      for (int m=0;m<2;m++){
        f32x4 v;
        #pragma unroll
        for (int r=0;r<4;r++) v[r] = a0[m][r] + a1[m][r]*(1.0f/4096.0f);
        *(f32x4*)&red[s][w][m][lane][0] = v;
      }
    }
    if (is_cmb){
      #pragma unroll
      for (int g=0;g<3;g++){
        f32x4 a0[2], a1[2];
        #pragma unroll
        for (int m=0;m<2;m++){ a0[m]=f32x4{0,0,0,0}; a1[m]=f32x4{0,0,0,0}; }
        #pragma unroll
        for (int i=0;i<3;i++)
          #pragma unroll
          for (int m=0;m<2;m++){
            a0[m] = mfma16(ah[m][i], gw_h[g][i], a0[m]);
            a1[m] = mfma16(ah[m][i], gw_l[g][i], a1[m]);
            a1[m] = mfma16(al[m][i], gw_h[g][i], a1[m]);
          }
        #pragma unroll
        for (int m=0;m<2;m++){
          f32x4 v;
          #pragma unroll
          for (int r=0;r<4;r++) v[r] = a0[m][r] + a1[m][r]*(1.0f/4096.0f);
          *(f32x4*)&redg[g][w][m][lane][0] = v;
        }
      }
    }
    __syncthreads();
    // ---- reduce: waves 0,1 logits; waves 2..4 gh (combine blocks) ----
    float sv[2][4];
    bool have_out = false;
    if (w < 2){
      const int s = w;
      float vm[2][4];
      #pragma unroll
      for (int m=0;m<2;m++){
        f32x4 sum = {0,0,0,0};
        #pragma unroll
        for (int ww=0; ww<8; ww++) sum += *(const f32x4*)&red[s][ww][m][lane][0];
        #pragma unroll
        for (int r=0;r<4;r++) vm[m][r] = sum[r];
      }
      if (t >= 1){
        have_out = true;
        const int v = s*4096 + bid*16 + col;
        const float bo = bo_reg[s];
        #pragma unroll
        for (int m=0;m<2;m++)
          #pragma unroll
          for (int r=0;r<4;r++){
            const int b = m*16 + kg*4 + r;
            const float p = vm[m][r] + bo;
            sv[m][r] = p;
            u64 key = packkey(p, v);
            #pragma unroll
            for (int off=1; off<16; off<<=1){
              u64 o = __shfl_xor((unsigned long long)key, off);
              if (o > key) key = o;
            }
            if (col == 0) atomicMax(&amkey[b], key);
          }
      }
    } else if (is_cmb && w < 5){
      const int g = w - 2;
      #pragma unroll
      for (int m=0;m<2;m++){
        f32x4 sum = {0,0,0,0};
        #pragma unroll
        for (int ww=0; ww<8; ww++) sum += *(const f32x4*)&redg[g][ww][m][lane][0];
        #pragma unroll
        for (int r=0;r<4;r++) ghl[g][m*16+kg*4+r][col] = sum[r];
      }
    }
    __syncthreads();
    // ---- post candidates (global argmax via L3 atomics) + arrive ----
    if (w == 0){
      if (t >= 1 && lane < 32)
        atomicMax(&slots32[(size_t)(t&3)*32 + lane], amkey[lane]);
      asm volatile("s_waitcnt vmcnt(0)" ::: "memory");   // maxes done before arrive
      if (lane == 0) AGENT_ADD(&bar[0], 1u);
    }
    if (have_out){                                       // off critical path
      const int v = w*4096 + bid*16 + col;
      #pragma unroll
      for (int m=0;m<2;m++)
        #pragma unroll
        for (int r=0;r<4;r++)
          out[(size_t)(m*16+kg*4+r)*((size_t)T_*V_) + (size_t)(t-1)*V_ + v] = sv[m][r];
    }
    if (t == 256) break;
    // =================== combine (blocks 0..47, all local) ===================
    if (is_cmb){
      if (w == 0) poll_cnt(&bar[0], 256u*(u32)(t+1));
      __syncthreads();
      int tok = 1;
      if (t > 0){
        u64 k = AGENT_LD(&slots32[(size_t)(t&3)*32 + cb]);
        tok = (int)(0xFFFFFFFFu - (u32)(k & 0xFFFFFFFFull));
      }
      const float* gp = gi_tab + (size_t)tok*2304 + ce;
      const float gir = gp[0]    + bir;
      const float giz = gp[768]  + biz;
      const float gin = gp[1536] + bin_;
      const int eo = tid & 15;
      const float ghr = ghl[0][cb][eo] + bhr;
      const float ghz = ghl[1][cb][eo] + bhz;
      const float ghn = ghl[2][cb][eo] + bhn;
      const float rr = 1.0f/(1.0f+expf(-(gir+ghr)));
      const float zz = 1.0f/(1.0f+expf(-(giz+ghz)));
      const float nn = tanhf(gin + rr*ghn);
      hreg = (1.0f-zz)*nn + zz*hreg;
      AGENT_ST(&h_pack[cb*768 + ce], packh(hreg));
      if (tid < 32) AGENT_ST(&slots32[(size_t)((t+2)&3)*32 + tid], 0ull);  // rotate-zero
      __syncthreads();                      // drains all waves' h stores (vmcnt0 @ barrier)
      if (tid == 0) AGENT_ADD(&bar[32], 1u);
    }
    // =================== wait h(t+1) ===================
    if (w == 0) poll_cnt(&bar[32], 48u*(u32)(t+1));
    __syncthreads();
  }
}

// ---------------- host ----------------
extern "C" void kernel_launch(void* const* d_in, const int* in_sizes, int n_in,
                              void* d_out, int out_size, void* d_ws, size_t ws_size,
                              hipStream_t stream){
  const float* latent = (const float*)d_in[0];
  const float* W_lat  = (const float*)d_in[1];
  const float* b_lat  = (const float*)d_in[2];
  const float* emb    = (const float*)d_in[3];
  const float* W_ih   = (const float*)d_in[4];
  const float* W_hh   = (const float*)d_in[5];
  const float* b_ih   = (const float*)d_in[6];
  const float* b_hh   = (const float*)d_in[7];
  const float* W_out  = (const float*)d_in[8];
  const float* b_out  = (const float*)d_in[9];
  float* out = (float*)d_out;
  (void)in_sizes; (void)n_in; (void)out_size; (void)ws_size;

  char* ws = (char*)d_ws;
  size_t off = 0;
  auto carve = [&](size_t bytes)->char*{
    char* p = ws + off; off += (bytes + 255) & ~(size_t)255; return p;
  };
  f16*      Wih_s  = (f16*)     carve((size_t)2*IH_PLANE*2);    //  7.08 MB
  f16*      Whh_s  = (f16*)     carve((size_t)2*IH_PLANE*2);    //  7.08 MB
  f16*      Wout_s = (f16*)     carve((size_t)2*OUT_PLANE*2);   // 25.17 MB
  float*    gi_tab = (float*)   carve((size_t)8192*2304*4);     // 75.50 MB
  float*    h_f32  = (float*)   carve((size_t)HP*4);
  u32*      h_pack = (u32*)     carve((size_t)HP*4);
  u64*      slots32= (u64*)     carve((size_t)4*32*8);
  unsigned* bar    = (unsigned*)carve(2048);
  // total ~115 MB of d_ws

  hipLaunchKernelGGL(prep_k, dim3(NB_CONV+NB_H0), dim3(256), 0, stream,
                     W_ih, W_hh, W_out, latent, W_lat, b_lat,
                     Wih_s, Whh_s, Wout_s, h_f32, h_pack, slots32, bar);
  hipLaunchKernelGGL(gitab_k, dim3(512), dim3(512), 0, stream, emb, Wih_s, gi_tab);

  void* kargs[] = {
    (void*)&Wout_s, (void*)&Whh_s, (void*)&gi_tab, (void*)&h_f32, (void*)&h_pack,
    (void*)&slots32, (void*)&b_ih, (void*)&b_hh, (void*)&b_out, (void*)&out, (void*)&bar
  };
  (void)hipLaunchCooperativeKernel((void*)decode_k, dim3(NBLK), dim3(512), kargs, 0, stream);
}

// Round 7
// 3365.714 us; speedup vs baseline: 1.5071x; 1.5071x over previous
//
#include <hip/hip_runtime.h>
#include <stdint.h>

// MoleculeDecoder r7: r4 skeleton + WIDE coherent h-broadcast.
// r4-r6 post-mortem: the h broadcast was 3.1M 8-byte sc1 L3 transactions/step
// (~8x wasted L3 slots, ~6-10us/step) — common to all three rounds; sync-side
// redesigns (r5 flags, r6 same-line atomics) were noise or regressions.
// r7 = r4 verbatim, but h fragments loaded as global_load_dwordx4 sc0 sc1
// (32B contiguous per fragment), batched issue + single vmcnt(0) + sched_barrier.

typedef unsigned long long u64;
typedef unsigned int u32;
typedef _Float16 f16;
using half8 = __attribute__((ext_vector_type(8))) _Float16;
using f32x4 = __attribute__((ext_vector_type(4))) float;
using uint4v = __attribute__((ext_vector_type(4))) unsigned int;

#define E_ 768
#define V_ 8192
#define T_ 256
#define HP 24576            // 32*768 (one h plane, elements)
#define IH_PLANE (2304*768)
#define OUT_PLANE (8192*768)
#define NBLK 256

#define AGENT_LD(p)    __hip_atomic_load((p), __ATOMIC_RELAXED, __HIP_MEMORY_SCOPE_AGENT)
#define AGENT_ST(p,v)  __hip_atomic_store((p), (v), __ATOMIC_RELAXED, __HIP_MEMORY_SCOPE_AGENT)
#define AGENT_ADD(p,v) __hip_atomic_fetch_add((p), (v), __ATOMIC_RELAXED, __HIP_MEMORY_SCOPE_AGENT)

__device__ __forceinline__ f32x4 mfma16(half8 a, half8 b, f32x4 c){
  return __builtin_amdgcn_mfma_f32_16x16x32_f16(a, b, c, 0, 0, 0);
}
__device__ __forceinline__ void split2(float f, f16& hi, f16& lo){
  f16 h = (f16)f; hi = h; lo = (f16)((f - (float)h) * 4096.0f);
}
__device__ __forceinline__ u32 packh(float f){
  f16 h, l; split2(f, h, l);
  return (u32)__builtin_bit_cast(unsigned short, h) |
         ((u32)__builtin_bit_cast(unsigned short, l) << 16);
}
__device__ __forceinline__ u64 packkey(float f, int v){
  u32 fb = __float_as_uint(f);
  u32 s  = fb ^ ((u32)((int32_t)fb>>31) | 0x80000000u);
  return ((u64)s<<32) | (u64)(0xFFFFFFFFu - (u32)v);   // ties -> smaller idx wins
}

// ---------------- prep: split weights; h0 (f32 + packed hi/lo); zero barrier ----------------
#define NB_CONV 1200
#define NB_H0   96
#define NG_IH   221184      // 2304*768/8
#define NG_ALL  1228800     // (2*2304 + 8192)*768/8

__global__ __launch_bounds__(256) void prep_k(
    const float* __restrict__ W_ih, const float* __restrict__ W_hh, const float* __restrict__ W_out,
    const float* __restrict__ latent, const float* __restrict__ W_lat, const float* __restrict__ b_lat,
    f16* __restrict__ Wih_s, f16* __restrict__ Whh_s, f16* __restrict__ Wout_s,
    float* __restrict__ h_f32, u32* __restrict__ h_pack, unsigned* __restrict__ bar)
{
  int blk = blockIdx.x;
  if (blk < NB_CONV){
    for (int g = blk*256 + threadIdx.x; g < NG_ALL; g += NB_CONV*256){
      const float* src; f16* hi; f16* lo; int off;
      if (g < NG_IH)        { src=W_ih; hi=Wih_s; lo=Wih_s+IH_PLANE; off=g*8; }
      else if (g < 2*NG_IH) { src=W_hh; hi=Whh_s; lo=Whh_s+IH_PLANE; off=(g-NG_IH)*8; }
      else                  { src=W_out; hi=Wout_s; lo=Wout_s+OUT_PLANE; off=(g-2*NG_IH)*8; }
      float4 a = *(const float4*)(src+off);
      float4 b = *(const float4*)(src+off+4);
      float fs[8] = {a.x,a.y,a.z,a.w,b.x,b.y,b.z,b.w};
      half8 vh, vl;
      #pragma unroll
      for (int j=0;j<8;j++){ f16 h,l; split2(fs[j],h,l); vh[j]=h; vl[j]=l; }
      *(half8*)(hi+off) = vh;
      *(half8*)(lo+off) = vl;
    }
  } else {
    if (blk==NB_CONV) bar[threadIdx.x] = 0;        // zero all barrier counters
    int tid = (blk-NB_CONV)*256 + threadIdx.x;     // 0..24575
    int b = tid/768, e = tid - b*768;
    const float4* wr = (const float4*)(W_lat + (size_t)e*768);
    const float4* xr = (const float4*)(latent + (size_t)b*768);
    float s0=0.f,s1=0.f,s2=0.f,s3=0.f;
    for (int k=0;k<192;k++){
      float4 w = wr[k]; float4 x = xr[k];
      s0 += w.x*x.x; s1 += w.y*x.y; s2 += w.z*x.z; s3 += w.w*x.w;
    }
    float acc = b_lat[e] + ((s0+s1)+(s2+s3));
    h_f32[b*768+e] = acc;
    h_pack[b*768+e] = packh(acc);
  }
}

// ---------------- gi table: gi_tab[tok][2304] = (W_ih @ emb[tok])  (no bias), f32 ----------------
__global__ __launch_bounds__(512) void gitab_k(
    const float* __restrict__ emb, const f16* __restrict__ Wih_s, float* __restrict__ gi_tab)
{
  __shared__ float red[3][8][2][64][4];
  const int bid = blockIdx.x, tid = threadIdx.x;
  const int tb = bid>>1, half = bid&1;
  const int w = tid>>6, lane = tid&63, col = lane&15, kg = lane>>4, kc = w;
  half8 ah[2][3], al[2][3];
  #pragma unroll
  for (int m=0;m<2;m++)
    #pragma unroll
    for (int i=0;i<3;i++){
      const float* src = emb + (size_t)(tb*32 + m*16 + col)*768 + kc*96 + i*32 + kg*8;
      float4 x0 = *(const float4*)src, x1 = *(const float4*)(src+4);
      float fs[8] = {x0.x,x0.y,x0.z,x0.w,x1.x,x1.y,x1.z,x1.w};
      half8 vh, vl;
      #pragma unroll
      for (int j=0;j<8;j++){ f16 h,l; split2(fs[j],h,l); vh[j]=h; vl[j]=l; }
      ah[m][i]=vh; al[m][i]=vl;
    }
  for (int g=0; g<24; ++g){
    #pragma unroll
    for (int j=0;j<3;j++){
      const int nt = half*72 + g*3 + j;
      f32x4 a0[2], a1[2];
      #pragma unroll
      for (int m=0;m<2;m++){ a0[m]=f32x4{0,0,0,0}; a1[m]=f32x4{0,0,0,0}; }
      #pragma unroll
      for (int i=0;i<3;i++){
        size_t o = (size_t)(nt*16+col)*768 + kc*96 + i*32 + kg*8;
        half8 bh = *(const half8*)(Wih_s + o);
        half8 bl = *(const half8*)(Wih_s + IH_PLANE + o);
        #pragma unroll
        for (int m=0;m<2;m++){
          a0[m] = mfma16(ah[m][i], bh, a0[m]);
          a1[m] = mfma16(ah[m][i], bl, a1[m]);
          a1[m] = mfma16(al[m][i], bh, a1[m]);
        }
      }
      #pragma unroll
      for (int m=0;m<2;m++){
        f32x4 v;
        #pragma unroll
        for (int r=0;r<4;r++) v[r] = a0[m][r] + a1[m][r]*(1.0f/4096.0f);
        *(f32x4*)&red[j][w][m][lane][0] = v;
      }
    }
    __syncthreads();
    if (w < 6){
      const int j = w>>1, m = w&1;
      f32x4 s = {0,0,0,0};
      #pragma unroll
      for (int ww=0; ww<8; ww++) s += *(const f32x4*)&red[j][ww][m][lane][0];
      const int nt = half*72 + g*3 + j;
      const int tokr = tb*32 + m*16 + kg*4;
      #pragma unroll
      for (int r=0;r<4;r++)
        gi_tab[(size_t)(tokr+r)*2304 + nt*16 + col] = s[r];
    }
    __syncthreads();
  }
}

// ---------------- grid barrier: NO fences; two-level arrive; relaxed coherent polls ----------------
// bar layout: bar[g*16], g=0..7 : level-1 group counters (separate lines)
//             bar[128]          : level-2 root counter
__device__ __forceinline__ void gridbar(unsigned* bar, unsigned target){
  __syncthreads();   // drains each wave's vmem ops (sc1 stores now globally visible)
  if (threadIdx.x == 0){
    const int g = blockIdx.x & 7;
    unsigned old = AGENT_ADD(&bar[g*16], 1u);
    if (old == 32u*target - 1u)            // last arriver of this group this round
      AGENT_ADD(&bar[128], 1u);
    int spins = 0;
    while (AGENT_LD(&bar[128]) < 8u*target){
      __builtin_amdgcn_s_sleep(1);
      if ((++spins & 2047) == 0)           // liveness insurance (RMW always coherent)
        AGENT_ADD(&bar[128], 0u);
    }
  }
  __syncthreads();
}

// ---------------- persistent decode kernel (cooperative, 256 x 512) ----------------
__global__ __launch_bounds__(512, 2) void decode_k(
    const f16* __restrict__ Wout_s, const f16* __restrict__ Whh_s, const float* __restrict__ gi_tab,
    float* __restrict__ gh_buf, const float* __restrict__ h_f32, u32* __restrict__ h_pack,
    u64* __restrict__ candbuf, const float* __restrict__ b_ih, const float* __restrict__ b_hh,
    const float* __restrict__ b_out, float* __restrict__ out, unsigned* __restrict__ bar)
{
  __shared__ float red[3][8][2][64][4];   // 48 KB
  __shared__ u64 amkey[32];
  const int bid = blockIdx.x, tid = threadIdx.x;
  const int w = tid>>6, lane = tid&63, col = lane&15, kg = lane>>4, kc = w;

  // ---- persistent B fragments (held in VGPRs for the whole kernel) ----
  const f16* srcH[3] = {Wout_s, Wout_s, (bid<144)? Whh_s : Wout_s};
  const f16* srcL[3] = {Wout_s+OUT_PLANE, Wout_s+OUT_PLANE,
                        (bid<144)? Whh_s+IH_PLANE : Wout_s+OUT_PLANE};
  const int  rowb[3] = {bid*16, 4096+bid*16, (bid<144)? bid*16 : 0};
  half8 bf_h[3][3], bf_l[3][3];
  #pragma unroll
  for (int s=0;s<3;s++)
    #pragma unroll
    for (int i=0;i<3;i++){
      size_t o = (size_t)(rowb[s]+col)*768 + kc*96 + i*32 + kg*8;
      bf_h[s][i] = *(const half8*)(srcH[s] + o);
      bf_l[s][i] = *(const half8*)(srcL[s] + o);
    }
  float bo_reg[2];
  bo_reg[0] = b_out[bid*16 + col];
  bo_reg[1] = b_out[4096 + bid*16 + col];

  // combine-role hoists (blocks 0..47 own h elements)
  int cb = 0, ce = 0; float hreg = 0.f;
  float bir=0,biz=0,bin_=0,bhr=0,bhz=0,bhn=0;
  if (bid < 48){
    int gid = bid*512 + tid;
    cb = gid/768; ce = gid - cb*768;
    hreg = h_f32[cb*768 + ce];
    bir=b_ih[ce]; biz=b_ih[768+ce]; bin_=b_ih[1536+ce];
    bhr=b_hh[ce]; bhz=b_hh[768+ce]; bhn=b_hh[1536+ce];
  }

  unsigned bt = 0;
  for (int t=0; t<=256; ++t){
    // =================== phase A ===================
    if (tid < 32) amkey[tid] = 0;
    // A-frags: WIDE coherent loads of packed h (2x dwordx4 per fragment, sc0 sc1
    // = bypass L1/L2, L3-served). Batched issue, single vmcnt, sched fence.
    uint4v qa[2][3], qb[2][3];
    #pragma unroll
    for (int m=0;m<2;m++)
      #pragma unroll
      for (int i=0;i<3;i++){
        const u32* hp = h_pack + (m*16+col)*768 + kc*96 + i*32 + kg*8;
        asm volatile("global_load_dwordx4 %0, %1, off sc0 sc1"
                     : "=&v"(qa[m][i]) : "v"(hp));
        asm volatile("global_load_dwordx4 %0, %1, off offset:16 sc0 sc1"
                     : "=&v"(qb[m][i]) : "v"(hp));
      }
    asm volatile("s_waitcnt vmcnt(0)" ::: "memory");
    __builtin_amdgcn_sched_barrier(0);
    half8 ah[2][3], al[2][3];
    #pragma unroll
    for (int m=0;m<2;m++)
      #pragma unroll
      for (int i=0;i<3;i++){
        uint4v wh, wl;
        u32 d[8] = {qa[m][i][0],qa[m][i][1],qa[m][i][2],qa[m][i][3],
                    qb[m][i][0],qb[m][i][1],qb[m][i][2],qb[m][i][3]};
        #pragma unroll
        for (int j=0;j<4;j++){
          u32 w0 = d[2*j], w1 = d[2*j+1];
          wh[j] = (w0 & 0xffffu) | (w1 << 16);
          wl[j] = (w0 >> 16) | (w1 & 0xffff0000u);
        }
        ah[m][i] = __builtin_bit_cast(half8, wh);
        al[m][i] = __builtin_bit_cast(half8, wl);
      }
    #pragma unroll
    for (int s=0;s<3;s++){
      f32x4 a0[2], a1[2];
      #pragma unroll
      for (int m=0;m<2;m++){ a0[m]=f32x4{0,0,0,0}; a1[m]=f32x4{0,0,0,0}; }
      #pragma unroll
      for (int i=0;i<3;i++)
        #pragma unroll
        for (int m=0;m<2;m++){
          a0[m] = mfma16(ah[m][i], bf_h[s][i], a0[m]);
          a1[m] = mfma16(ah[m][i], bf_l[s][i], a1[m]);
          a1[m] = mfma16(al[m][i], bf_h[s][i], a1[m]);
        }
      #pragma unroll
      for (int m=0;m<2;m++){
        f32x4 v;
        #pragma unroll
        for (int r=0;r<4;r++) v[r] = a0[m][r] + a1[m][r]*(1.0f/4096.0f);
        *(f32x4*)&red[s][w][m][lane][0] = v;
      }
    }
    __syncthreads();
    float sv[2][4];                       // deferred logit stores
    bool have_out = false;
    if (w < 3){
      const int s = w;
      float vm[2][4];
      #pragma unroll
      for (int m=0;m<2;m++){
        f32x4 sum = {0,0,0,0};
        #pragma unroll
        for (int ww=0; ww<8; ww++) sum += *(const f32x4*)&red[s][ww][m][lane][0];
        #pragma unroll
        for (int r=0;r<4;r++) vm[m][r] = sum[r];
      }
      if (s < 2){
        if (t >= 1){
          have_out = true;
          const int v = s*4096 + bid*16 + col;
          const float bo = bo_reg[s];
          #pragma unroll
          for (int m=0;m<2;m++)
            #pragma unroll
            for (int r=0;r<4;r++){
              const int b = m*16 + kg*4 + r;
              const float p = vm[m][r] + bo;
              sv[m][r] = p;
              u64 key = packkey(p, v);
              #pragma unroll
              for (int off=1; off<16; off<<=1){
                u64 o = __shfl_xor((unsigned long long)key, off);
                if (o > key) key = o;
              }
              if (col == 0) atomicMax(&amkey[b], key);
            }
        }
      } else if (bid < 144){
        const int gr = bid*16 + col;
        #pragma unroll
        for (int m=0;m<2;m++)
          #pragma unroll
          for (int r=0;r<4;r++)
            AGENT_ST(&gh_buf[(m*16+kg*4+r)*2304 + gr], vm[m][r]);
      }
    }
    __syncthreads();                      // amkey final; all waves' vmem drained
    if (t >= 1 && tid < 32) AGENT_ST(&candbuf[(size_t)bid*32 + tid], amkey[tid]);
    if (have_out){                        // off critical path (before barrier anyway)
      const int v = w*4096 + bid*16 + col;
      #pragma unroll
      for (int m=0;m<2;m++)
        #pragma unroll
        for (int r=0;r<4;r++)
          out[(size_t)(m*16+kg*4+r)*((size_t)T_*V_) + (size_t)(t-1)*V_ + v] = sv[m][r];
    }
    if (t == 256) break;
    gridbar(bar, ++bt);
    // =================== phase B ===================
    if (bid < 48){
      int tok = 1;
      if (t > 0){
        u64 k = 0;
        #pragma unroll
        for (int j=0;j<4;j++){
          u64 c = AGENT_LD(&candbuf[(size_t)(lane + 64*j)*32 + cb]);
          if (c > k) k = c;
        }
        #pragma unroll
        for (int off=1; off<64; off<<=1){
          u64 o = __shfl_xor((unsigned long long)k, off);
          if (o > k) k = o;
        }
        tok = (int)(0xFFFFFFFFu - (unsigned)(k & 0xFFFFFFFFull));
      }
      const float* gp = gi_tab + (size_t)tok*2304 + ce;
      const float gir = gp[0]    + bir;
      const float giz = gp[768]  + biz;
      const float gin = gp[1536] + bin_;
      float* hb = gh_buf + cb*2304 + ce;
      const float ghr = AGENT_LD(hb)        + bhr;
      const float ghz = AGENT_LD(hb + 768)  + bhz;
      const float ghn = AGENT_LD(hb + 1536) + bhn;
      const float rr = 1.0f/(1.0f+expf(-(gir+ghr)));
      const float zz = 1.0f/(1.0f+expf(-(giz+ghz)));
      const float nn = tanhf(gin + rr*ghn);
      hreg = (1.0f-zz)*nn + zz*hreg;
      AGENT_ST(&h_pack[cb*768 + ce], packh(hreg));
    }
    gridbar(bar, ++bt);
  }
}

// ---------------- host ----------------
extern "C" void kernel_launch(void* const* d_in, const int* in_sizes, int n_in,
                              void* d_out, int out_size, void* d_ws, size_t ws_size,
                              hipStream_t stream){
  const float* latent = (const float*)d_in[0];
  const float* W_lat  = (const float*)d_in[1];
  const float* b_lat  = (const float*)d_in[2];
  const float* emb    = (const float*)d_in[3];
  const float* W_ih   = (const float*)d_in[4];
  const float* W_hh   = (const float*)d_in[5];
  const float* b_ih   = (const float*)d_in[6];
  const float* b_hh   = (const float*)d_in[7];
  const float* W_out  = (const float*)d_in[8];
  const float* b_out  = (const float*)d_in[9];
  float* out = (float*)d_out;
  (void)in_sizes; (void)n_in; (void)out_size; (void)ws_size;

  char* ws = (char*)d_ws;
  size_t off = 0;
  auto carve = [&](size_t bytes)->char*{
    char* p = ws + off; off += (bytes + 255) & ~(size_t)255; return p;
  };
  f16*      Wih_s  = (f16*)     carve((size_t)2*IH_PLANE*2);    //  7.08 MB
  f16*      Whh_s  = (f16*)     carve((size_t)2*IH_PLANE*2);    //  7.08 MB
  f16*      Wout_s = (f16*)     carve((size_t)2*OUT_PLANE*2);   // 25.17 MB
  float*    gi_tab = (float*)   carve((size_t)8192*2304*4);     // 75.50 MB
  float*    gh_buf = (float*)   carve((size_t)32*2304*4);       //  0.29 MB
  float*    h_f32  = (float*)   carve((size_t)HP*4);
  u32*      h_pack = (u32*)     carve((size_t)HP*4);
  u64*      candbuf= (u64*)     carve((size_t)256*32*8);
  unsigned* bar    = (unsigned*)carve(2048);
  // total ~115.5 MB of d_ws

  hipLaunchKernelGGL(prep_k, dim3(NB_CONV+NB_H0), dim3(256), 0, stream,
                     W_ih, W_hh, W_out, latent, W_lat, b_lat,
                     Wih_s, Whh_s, Wout_s, h_f32, h_pack, bar);
  hipLaunchKernelGGL(gitab_k, dim3(512), dim3(512), 0, stream, emb, Wih_s, gi_tab);

  void* kargs[] = {
    (void*)&Wout_s, (void*)&Whh_s, (void*)&gi_tab, (void*)&gh_buf, (void*)&h_f32,
    (void*)&h_pack, (void*)&candbuf, (void*)&b_ih, (void*)&b_hh, (void*)&b_out,
    (void*)&out, (void*)&bar
  };
  (void)hipLaunchCooperativeKernel((void*)decode_k, dim3(NBLK), dim3(512), kargs, 0, stream);
}

// Round 8
// 3082.816 us; speedup vs baseline: 1.6454x; 1.0918x over previous
//
#include <hip/hip_runtime.h>
#include <stdint.h>

// MoleculeDecoder r8: r7 + L2-routed h ring + packed gi_tab + transposed candbuf
//                     + out-stores off the barrier-arrival path.
// r7 post-mortem: h broadcast = 25 MB/step of sc0sc1 (L2-bypass) reads, all
// served by L3; candbuf gather = 98k scattered 8B sc01 reads; out-store drain
// inside bar1 arrival. r8 routes h through per-XCD L2 via a 257-deep ring with
// normal cached reads (fresh addresses/step => no stale-L2 hazard; one-time
// acquire fence kills poison), packs gi_tab to u32 hi/lo, transposes candbuf,
// moves out stores after bar1.

typedef unsigned long long u64;
typedef unsigned int u32;
typedef _Float16 f16;
using half8 = __attribute__((ext_vector_type(8))) _Float16;
using f32x4 = __attribute__((ext_vector_type(4))) float;
using uint4v = __attribute__((ext_vector_type(4))) unsigned int;

#define E_ 768
#define V_ 8192
#define T_ 256
#define HP 24576            // 32*768 (one h plane, elements)
#define IH_PLANE (2304*768)
#define OUT_PLANE (8192*768)
#define NBLK 256

#define AGENT_LD(p)    __hip_atomic_load((p), __ATOMIC_RELAXED, __HIP_MEMORY_SCOPE_AGENT)
#define AGENT_ST(p,v)  __hip_atomic_store((p), (v), __ATOMIC_RELAXED, __HIP_MEMORY_SCOPE_AGENT)
#define AGENT_ADD(p,v) __hip_atomic_fetch_add((p), (v), __ATOMIC_RELAXED, __HIP_MEMORY_SCOPE_AGENT)

__device__ __forceinline__ f32x4 mfma16(half8 a, half8 b, f32x4 c){
  return __builtin_amdgcn_mfma_f32_16x16x32_f16(a, b, c, 0, 0, 0);
}
__device__ __forceinline__ void split2(float f, f16& hi, f16& lo){
  f16 h = (f16)f; hi = h; lo = (f16)((f - (float)h) * 4096.0f);
}
__device__ __forceinline__ u32 packh(float f){
  f16 h, l; split2(f, h, l);
  return (u32)__builtin_bit_cast(unsigned short, h) |
         ((u32)__builtin_bit_cast(unsigned short, l) << 16);
}
__device__ __forceinline__ float unpackh(u32 u){
  f16 h = __builtin_bit_cast(f16, (unsigned short)(u & 0xffffu));
  f16 l = __builtin_bit_cast(f16, (unsigned short)(u >> 16));
  return (float)h + (float)l * (1.0f/4096.0f);
}
__device__ __forceinline__ u64 packkey(float f, int v){
  u32 fb = __float_as_uint(f);
  u32 s  = fb ^ ((u32)((int32_t)fb>>31) | 0x80000000u);
  return ((u64)s<<32) | (u64)(0xFFFFFFFFu - (u32)v);   // ties -> smaller idx wins
}

// ---------------- prep: split weights; h0 (f32 + packed ring slot 0); zero barrier ----------------
#define NB_CONV 1200
#define NB_H0   96
#define NG_IH   221184      // 2304*768/8
#define NG_ALL  1228800     // (2*2304 + 8192)*768/8

__global__ __launch_bounds__(256) void prep_k(
    const float* __restrict__ W_ih, const float* __restrict__ W_hh, const float* __restrict__ W_out,
    const float* __restrict__ latent, const float* __restrict__ W_lat, const float* __restrict__ b_lat,
    f16* __restrict__ Wih_s, f16* __restrict__ Whh_s, f16* __restrict__ Wout_s,
    float* __restrict__ h_f32, u32* __restrict__ h_seq, unsigned* __restrict__ bar)
{
  int blk = blockIdx.x;
  if (blk < NB_CONV){
    for (int g = blk*256 + threadIdx.x; g < NG_ALL; g += NB_CONV*256){
      const float* src; f16* hi; f16* lo; int off;
      if (g < NG_IH)        { src=W_ih; hi=Wih_s; lo=Wih_s+IH_PLANE; off=g*8; }
      else if (g < 2*NG_IH) { src=W_hh; hi=Whh_s; lo=Whh_s+IH_PLANE; off=(g-NG_IH)*8; }
      else                  { src=W_out; hi=Wout_s; lo=Wout_s+OUT_PLANE; off=(g-2*NG_IH)*8; }
      float4 a = *(const float4*)(src+off);
      float4 b = *(const float4*)(src+off+4);
      float fs[8] = {a.x,a.y,a.z,a.w,b.x,b.y,b.z,b.w};
      half8 vh, vl;
      #pragma unroll
      for (int j=0;j<8;j++){ f16 h,l; split2(fs[j],h,l); vh[j]=h; vl[j]=l; }
      *(half8*)(hi+off) = vh;
      *(half8*)(lo+off) = vl;
    }
  } else {
    if (blk==NB_CONV) bar[threadIdx.x] = 0;        // zero all barrier counters
    int tid = (blk-NB_CONV)*256 + threadIdx.x;     // 0..24575
    int b = tid/768, e = tid - b*768;
    const float4* wr = (const float4*)(W_lat + (size_t)e*768);
    const float4* xr = (const float4*)(latent + (size_t)b*768);
    float s0=0.f,s1=0.f,s2=0.f,s3=0.f;
    for (int k=0;k<192;k++){
      float4 w = wr[k]; float4 x = xr[k];
      s0 += w.x*x.x; s1 += w.y*x.y; s2 += w.z*x.z; s3 += w.w*x.w;
    }
    float acc = b_lat[e] + ((s0+s1)+(s2+s3));
    h_f32[b*768+e] = acc;
    h_seq[b*768+e] = packh(acc);                   // ring slot 0
  }
}

// ---------------- gi table: gi_tab[tok][2304] = packed(W_ih @ emb[tok]) ----------------
__global__ __launch_bounds__(512) void gitab_k(
    const float* __restrict__ emb, const f16* __restrict__ Wih_s, u32* __restrict__ gi_tab)
{
  __shared__ float red[3][8][2][64][4];
  const int bid = blockIdx.x, tid = threadIdx.x;
  const int tb = bid>>1, half = bid&1;
  const int w = tid>>6, lane = tid&63, col = lane&15, kg = lane>>4, kc = w;
  half8 ah[2][3], al[2][3];
  #pragma unroll
  for (int m=0;m<2;m++)
    #pragma unroll
    for (int i=0;i<3;i++){
      const float* src = emb + (size_t)(tb*32 + m*16 + col)*768 + kc*96 + i*32 + kg*8;
      float4 x0 = *(const float4*)src, x1 = *(const float4*)(src+4);
      float fs[8] = {x0.x,x0.y,x0.z,x0.w,x1.x,x1.y,x1.z,x1.w};
      half8 vh, vl;
      #pragma unroll
      for (int j=0;j<8;j++){ f16 h,l; split2(fs[j],h,l); vh[j]=h; vl[j]=l; }
      ah[m][i]=vh; al[m][i]=vl;
    }
  for (int g=0; g<24; ++g){
    #pragma unroll
    for (int j=0;j<3;j++){
      const int nt = half*72 + g*3 + j;
      f32x4 a0[2], a1[2];
      #pragma unroll
      for (int m=0;m<2;m++){ a0[m]=f32x4{0,0,0,0}; a1[m]=f32x4{0,0,0,0}; }
      #pragma unroll
      for (int i=0;i<3;i++){
        size_t o = (size_t)(nt*16+col)*768 + kc*96 + i*32 + kg*8;
        half8 bh = *(const half8*)(Wih_s + o);
        half8 bl = *(const half8*)(Wih_s + IH_PLANE + o);
        #pragma unroll
        for (int m=0;m<2;m++){
          a0[m] = mfma16(ah[m][i], bh, a0[m]);
          a1[m] = mfma16(ah[m][i], bl, a1[m]);
          a1[m] = mfma16(al[m][i], bh, a1[m]);
        }
      }
      #pragma unroll
      for (int m=0;m<2;m++){
        f32x4 v;
        #pragma unroll
        for (int r=0;r<4;r++) v[r] = a0[m][r] + a1[m][r]*(1.0f/4096.0f);
        *(f32x4*)&red[j][w][m][lane][0] = v;
      }
    }
    __syncthreads();
    if (w < 6){
      const int j = w>>1, m = w&1;
      f32x4 s = {0,0,0,0};
      #pragma unroll
      for (int ww=0; ww<8; ww++) s += *(const f32x4*)&red[j][ww][m][lane][0];
      const int nt = half*72 + g*3 + j;
      const int tokr = tb*32 + m*16 + kg*4;
      #pragma unroll
      for (int r=0;r<4;r++)
        gi_tab[(size_t)(tokr+r)*2304 + nt*16 + col] = packh(s[r]);
    }
    __syncthreads();
  }
}

// ---------------- grid barrier: two-level tree, relaxed coherent, no fences ----------------
__device__ __forceinline__ void gridbar(unsigned* bar, unsigned target){
  __syncthreads();   // drains each wave's vmem ops (sc1 stores now globally visible)
  if (threadIdx.x == 0){
    const int g = blockIdx.x & 7;
    unsigned old = AGENT_ADD(&bar[g*16], 1u);
    if (old == 32u*target - 1u)
      AGENT_ADD(&bar[128], 1u);
    int spins = 0;
    while (AGENT_LD(&bar[128]) < 8u*target){
      __builtin_amdgcn_s_sleep(1);
      if ((++spins & 2047) == 0)
        AGENT_ADD(&bar[128], 0u);
    }
  }
  __syncthreads();
}

// ---------------- persistent decode kernel (cooperative, 256 x 512) ----------------
__global__ __launch_bounds__(512, 2) void decode_k(
    const f16* __restrict__ Wout_s, const f16* __restrict__ Whh_s, const u32* __restrict__ gi_tab,
    float* __restrict__ gh_buf, const float* __restrict__ h_f32, u32* __restrict__ h_seq,
    u64* __restrict__ candbufT, const float* __restrict__ b_ih, const float* __restrict__ b_hh,
    const float* __restrict__ b_out, float* __restrict__ out, unsigned* __restrict__ bar)
{
  __shared__ float red[3][8][2][64][4];   // 48 KB
  __shared__ u64 amkey[32];
  const int bid = blockIdx.x, tid = threadIdx.x;
  const int w = tid>>6, lane = tid&63, col = lane&15, kg = lane>>4, kc = w;

  // One-time L2/L1 invalidate: kill any stale (poison) lines before cached h reads.
  __builtin_amdgcn_fence(__ATOMIC_ACQUIRE, "agent");
  __syncthreads();

  // ---- persistent B fragments (held in VGPRs for the whole kernel) ----
  const f16* srcH[3] = {Wout_s, Wout_s, (bid<144)? Whh_s : Wout_s};
  const f16* srcL[3] = {Wout_s+OUT_PLANE, Wout_s+OUT_PLANE,
                        (bid<144)? Whh_s+IH_PLANE : Wout_s+OUT_PLANE};
  const int  rowb[3] = {bid*16, 4096+bid*16, (bid<144)? bid*16 : 0};
  half8 bf_h[3][3], bf_l[3][3];
  #pragma unroll
  for (int s=0;s<3;s++)
    #pragma unroll
    for (int i=0;i<3;i++){
      size_t o = (size_t)(rowb[s]+col)*768 + kc*96 + i*32 + kg*8;
      bf_h[s][i] = *(const half8*)(srcH[s] + o);
      bf_l[s][i] = *(const half8*)(srcL[s] + o);
    }
  float bo_reg[2];
  bo_reg[0] = b_out[bid*16 + col];
  bo_reg[1] = b_out[4096 + bid*16 + col];

  // combine-role hoists (blocks 0..47 own h elements)
  int cb = 0, ce = 0; float hreg = 0.f;
  float bir=0,biz=0,bin_=0,bhr=0,bhz=0,bhn=0;
  if (bid < 48){
    int gid = bid*512 + tid;
    cb = gid/768; ce = gid - cb*768;
    hreg = h_f32[cb*768 + ce];
    bir=b_ih[ce]; biz=b_ih[768+ce]; bin_=b_ih[1536+ce];
    bhr=b_hh[ce]; bhz=b_hh[768+ce]; bhn=b_hh[1536+ce];
  }

  unsigned bt = 0;
  for (int t=0; t<=256; ++t){
    // =================== phase A ===================
    if (tid < 32) amkey[tid] = 0;
    // A-frags: NORMAL CACHED wide loads from this step's ring slot (fresh
    // addresses each step -> no stale-L2 hazard; per-XCD L2 merges the 32
    // resident blocks' misses so L3 serves each line ~8x, not 256x).
    const u32* hbase = h_seq + (size_t)t*HP;
    uint4v qa[2][3], qb[2][3];
    #pragma unroll
    for (int m=0;m<2;m++)
      #pragma unroll
      for (int i=0;i<3;i++){
        const uint4v* hp = (const uint4v*)(hbase + (m*16+col)*768 + kc*96 + i*32 + kg*8);
        qa[m][i] = hp[0];
        qb[m][i] = hp[1];
      }
    half8 ah[2][3], al[2][3];
    #pragma unroll
    for (int m=0;m<2;m++)
      #pragma unroll
      for (int i=0;i<3;i++){
        uint4v wh, wl;
        u32 d[8] = {qa[m][i][0],qa[m][i][1],qa[m][i][2],qa[m][i][3],
                    qb[m][i][0],qb[m][i][1],qb[m][i][2],qb[m][i][3]};
        #pragma unroll
        for (int j=0;j<4;j++){
          u32 w0 = d[2*j], w1 = d[2*j+1];
          wh[j] = (w0 & 0xffffu) | (w1 << 16);
          wl[j] = (w0 >> 16) | (w1 & 0xffff0000u);
        }
        ah[m][i] = __builtin_bit_cast(half8, wh);
        al[m][i] = __builtin_bit_cast(half8, wl);
      }
    #pragma unroll
    for (int s=0;s<3;s++){
      f32x4 a0[2], a1[2];
      #pragma unroll
      for (int m=0;m<2;m++){ a0[m]=f32x4{0,0,0,0}; a1[m]=f32x4{0,0,0,0}; }
      #pragma unroll
      for (int i=0;i<3;i++)
        #pragma unroll
        for (int m=0;m<2;m++){
          a0[m] = mfma16(ah[m][i], bf_h[s][i], a0[m]);
          a1[m] = mfma16(ah[m][i], bf_l[s][i], a1[m]);
          a1[m] = mfma16(al[m][i], bf_h[s][i], a1[m]);
        }
      #pragma unroll
      for (int m=0;m<2;m++){
        f32x4 v;
        #pragma unroll
        for (int r=0;r<4;r++) v[r] = a0[m][r] + a1[m][r]*(1.0f/4096.0f);
        *(f32x4*)&red[s][w][m][lane][0] = v;
      }
    }
    __syncthreads();
    float sv[2][4];                       // deferred logit stores (cross-barrier)
    bool have_out = false;
    if (w < 3){
      const int s = w;
      float vm[2][4];
      #pragma unroll
      for (int m=0;m<2;m++){
        f32x4 sum = {0,0,0,0};
        #pragma unroll
        for (int ww=0; ww<8; ww++) sum += *(const f32x4*)&red[s][ww][m][lane][0];
        #pragma unroll
        for (int r=0;r<4;r++) vm[m][r] = sum[r];
      }
      if (s < 2){
        if (t >= 1){
          have_out = true;
          const int v = s*4096 + bid*16 + col;
          const float bo = bo_reg[s];
          #pragma unroll
          for (int m=0;m<2;m++)
            #pragma unroll
            for (int r=0;r<4;r++){
              const int b = m*16 + kg*4 + r;
              const float p = vm[m][r] + bo;
              sv[m][r] = p;
              u64 key = packkey(p, v);
              #pragma unroll
              for (int off=1; off<16; off<<=1){
                u64 o = __shfl_xor((unsigned long long)key, off);
                if (o > key) key = o;
              }
              if (col == 0) atomicMax(&amkey[b], key);
            }
        }
      } else if (bid < 144){
        const int gr = bid*16 + col;
        #pragma unroll
        for (int m=0;m<2;m++)
          #pragma unroll
          for (int r=0;r<4;r++)
            AGENT_ST(&gh_buf[(m*16+kg*4+r)*2304 + gr], vm[m][r]);
      }
    }
    __syncthreads();                      // amkey final
    // transposed candbuf: writer scatters 32 x 8B (uncontended), reader coalesced
    if (t >= 1 && tid < 32) AGENT_ST(&candbufT[(size_t)tid*256 + bid], amkey[tid]);
    if (t == 256){                        // last step: store logits, done
      if (have_out){
        const int v = w*4096 + bid*16 + col;
        #pragma unroll
        for (int m=0;m<2;m++)
          #pragma unroll
          for (int r=0;r<4;r++)
            out[(size_t)(m*16+kg*4+r)*((size_t)T_*V_) + (size_t)(t-1)*V_ + v] = sv[m][r];
      }
      break;
    }
    gridbar(bar, ++bt);
    // =================== out stores (off barrier-arrival path) + phase B ===================
    if (bid >= 48){
      if (have_out){
        const int v = w*4096 + bid*16 + col;
        #pragma unroll
        for (int m=0;m<2;m++)
          #pragma unroll
          for (int r=0;r<4;r++)
            out[(size_t)(m*16+kg*4+r)*((size_t)T_*V_) + (size_t)(t-1)*V_ + v] = sv[m][r];
      }
    } else {
      int tok = 1;
      if (t > 0){
        u64 k = 0;
        #pragma unroll
        for (int j=0;j<4;j++){
          u64 c = AGENT_LD(&candbufT[(size_t)cb*256 + lane + 64*j]);
          if (c > k) k = c;
        }
        #pragma unroll
        for (int off=1; off<64; off<<=1){
          u64 o = __shfl_xor((unsigned long long)k, off);
          if (o > k) k = o;
        }
        tok = (int)(0xFFFFFFFFu - (unsigned)(k & 0xFFFFFFFFull));
      }
      const u32* gp = gi_tab + (size_t)tok*2304 + ce;   // plain cached loads (read-only)
      const float gir = unpackh(gp[0])    + bir;
      const float giz = unpackh(gp[768])  + biz;
      const float gin = unpackh(gp[1536]) + bin_;
      float* hb = gh_buf + cb*2304 + ce;
      const float ghr = AGENT_LD(hb)        + bhr;
      const float ghz = AGENT_LD(hb + 768)  + bhz;
      const float ghn = AGENT_LD(hb + 1536) + bhn;
      const float rr = 1.0f/(1.0f+expf(-(gir+ghr)));
      const float zz = 1.0f/(1.0f+expf(-(giz+ghz)));
      const float nn = tanhf(gin + rr*ghn);
      hreg = (1.0f-zz)*nn + zz*hreg;
      AGENT_ST(&h_seq[(size_t)(t+1)*HP + cb*768 + ce], packh(hreg));  // next ring slot
      if (have_out){                       // after h store: off gi-load path
        const int v = w*4096 + bid*16 + col;
        #pragma unroll
        for (int m=0;m<2;m++)
          #pragma unroll
          for (int r=0;r<4;r++)
            out[(size_t)(m*16+kg*4+r)*((size_t)T_*V_) + (size_t)(t-1)*V_ + v] = sv[m][r];
      }
    }
    gridbar(bar, ++bt);
  }
}

// ---------------- host ----------------
extern "C" void kernel_launch(void* const* d_in, const int* in_sizes, int n_in,
                              void* d_out, int out_size, void* d_ws, size_t ws_size,
                              hipStream_t stream){
  const float* latent = (const float*)d_in[0];
  const float* W_lat  = (const float*)d_in[1];
  const float* b_lat  = (const float*)d_in[2];
  const float* emb    = (const float*)d_in[3];
  const float* W_ih   = (const float*)d_in[4];
  const float* W_hh   = (const float*)d_in[5];
  const float* b_ih   = (const float*)d_in[6];
  const float* b_hh   = (const float*)d_in[7];
  const float* W_out  = (const float*)d_in[8];
  const float* b_out  = (const float*)d_in[9];
  float* out = (float*)d_out;
  (void)in_sizes; (void)n_in; (void)out_size; (void)ws_size;

  char* ws = (char*)d_ws;
  size_t off = 0;
  auto carve = [&](size_t bytes)->char*{
    char* p = ws + off; off += (bytes + 255) & ~(size_t)255; return p;
  };
  f16*      Wih_s  = (f16*)     carve((size_t)2*IH_PLANE*2);    //  7.08 MB
  f16*      Whh_s  = (f16*)     carve((size_t)2*IH_PLANE*2);    //  7.08 MB
  f16*      Wout_s = (f16*)     carve((size_t)2*OUT_PLANE*2);   // 25.17 MB
  u32*      gi_tab = (u32*)     carve((size_t)8192*2304*4);     // 37.75 MB (packed)
  float*    gh_buf = (float*)   carve((size_t)32*2304*4);       //  0.29 MB
  float*    h_f32  = (float*)   carve((size_t)HP*4);            //  0.10 MB
  u32*      h_seq  = (u32*)     carve((size_t)257*HP*4);        // 25.26 MB ring
  u64*      candbufT=(u64*)     carve((size_t)32*256*8);        //  0.07 MB
  unsigned* bar    = (unsigned*)carve(2048);
  // total ~103 MB of d_ws (was ~115.5)

  hipLaunchKernelGGL(prep_k, dim3(NB_CONV+NB_H0), dim3(256), 0, stream,
                     W_ih, W_hh, W_out, latent, W_lat, b_lat,
                     Wih_s, Whh_s, Wout_s, h_f32, h_seq, bar);
  hipLaunchKernelGGL(gitab_k, dim3(512), dim3(512), 0, stream, emb, Wih_s, gi_tab);

  void* kargs[] = {
    (void*)&Wout_s, (void*)&Whh_s, (void*)&gi_tab, (void*)&gh_buf, (void*)&h_f32,
    (void*)&h_seq, (void*)&candbufT, (void*)&b_ih, (void*)&b_hh, (void*)&b_out,
    (void*)&out, (void*)&bar
  };
  (void)hipLaunchCooperativeKernel((void*)decode_k, dim3(NBLK), dim3(512), kargs, 0, stream);
}